// Round 1
// baseline (206.791 us; speedup 1.0000x reference)
//
#include <hip/hip_runtime.h>
#include <hip/hip_bf16.h>
#include <math.h>

// Problem constants (B=4096, D=128, T=0.5 -> 1/T = 2)
#define BB       4096
#define N2       8192          // 2B rows of z
#define DIMS     128
#define NT       64            // number of 128-row tiles per matrix side
#define NJOBS    (NT * (NT + 1) / 2)   // 2080 upper-triangle tile jobs
#define TILE     128
#define LDS_PAD  8             // bf16 pad per row: breaks 256B-stride 16B-group conflicts
#define LDS_ROWW (DIMS + LDS_PAD)  // 136 shorts = 272 B

// z rows are pre-scaled by ZSCALE so the MFMA dot directly yields
// sim * 2*log2(e), i.e. exp(sim/T) = exp2(acc). ZSCALE^2 = 2.8853900818.
#define ZSCALE   1.6986436f
// diagonal term exp(2 * |z_r|^2) ~= exp(2) — subtracted in finalize.
#define DIAG_E2  7.38905609893065f

typedef __attribute__((ext_vector_type(8))) short short8;   // 8 x bf16 (4 VGPRs)
typedef __attribute__((ext_vector_type(4))) float float4v;  // MFMA C/D

// ---------------------------------------------------------------------------
// Kernel 1: normalize rows (fp32), compute positives (fp32), write z as
// bf16 scaled by ZSCALE. Also zeroes denom accumulators and the completion
// counter. One wave per row-pair r: emb_i[r] -> z[r], emb_j[r] -> z[r+B].
// ---------------------------------------------------------------------------
__global__ __launch_bounds__(256) void norm_kernel(
    const float* __restrict__ emb_i, const float* __restrict__ emb_j,
    __hip_bfloat16* __restrict__ z, float* __restrict__ pos,
    float* __restrict__ denom, unsigned int* __restrict__ cnt) {
  if (blockIdx.x < N2 / 256) denom[blockIdx.x * 256 + threadIdx.x] = 0.0f;
  if (blockIdx.x == N2 / 256 && threadIdx.x == 0) cnt[0] = 0u;

  int gw   = (blockIdx.x * blockDim.x + threadIdx.x) >> 6;  // row pair
  int lane = threadIdx.x & 63;
  if (gw >= BB) return;

  const float2* ei = (const float2*)(emb_i + (size_t)gw * DIMS);
  const float2* ej = (const float2*)(emb_j + (size_t)gw * DIMS);
  float2 a = ei[lane];
  float2 b = ej[lane];

  float sa = a.x * a.x + a.y * a.y;
  float sb = b.x * b.x + b.y * b.y;
  #pragma unroll
  for (int m = 32; m; m >>= 1) {
    sa += __shfl_xor(sa, m, 64);
    sb += __shfl_xor(sb, m, 64);
  }
  float inva = 1.0f / fmaxf(sqrtf(sa), 1e-12f);
  float invb = 1.0f / fmaxf(sqrtf(sb), 1e-12f);

  float zi0 = a.x * inva, zi1 = a.y * inva;
  float zj0 = b.x * invb, zj1 = b.y * invb;

  // positive pair dot in unscaled fp32 (matches reference's fp32 einsum)
  float p = zi0 * zj0 + zi1 * zj1;
  #pragma unroll
  for (int m = 32; m; m >>= 1) p += __shfl_xor(p, m, 64);
  if (lane == 0) pos[gw] = p;

  __hip_bfloat162* zr_i = (__hip_bfloat162*)(z + (size_t)gw * DIMS);
  __hip_bfloat162* zr_j = (__hip_bfloat162*)(z + (size_t)(gw + BB) * DIMS);
  __hip_bfloat162 vi, vj;
  vi.x = __float2bfloat16(zi0 * ZSCALE); vi.y = __float2bfloat16(zi1 * ZSCALE);
  vj.x = __float2bfloat16(zj0 * ZSCALE); vj.y = __float2bfloat16(zj1 * ZSCALE);
  zr_i[lane] = vi;
  zr_j[lane] = vj;
}

// ---------------------------------------------------------------------------
// Kernel 2: symmetric fused sim-GEMM + exp2 + row/col sums + fused finalize.
// sim = z z^T is symmetric; job j covers the 128x128 tile (I,J), I<=J, over
// the 64x64 tile grid (2080 jobs). Off-diagonal tiles feed BOTH row sums
// (reduce over lanes, C-layout col=lane&15) and column sums (reduce over the
// 4 C-regs + shfl_xor over quads, C-layout row=quad*4+reg). Diagonal tiles
// are computed fully and feed row sums only. MFMA dot is bit-identical under
// operand transpose, so each pair contributes the same value it did before.
// Block = 256 threads (4 waves); wave owns 32 rows (2 rowtiles of A pinned in
// VGPRs), B tile (128 cols x 128 dims) staged once in LDS. Last block to
// finish runs the log-sum finalize (device-scope atomic counter).
// ---------------------------------------------------------------------------
__global__ __launch_bounds__(256, 4) void simloss_sym(
    const __hip_bfloat16* __restrict__ z, float* __restrict__ denom,
    const float* __restrict__ pos, unsigned int* __restrict__ cnt,
    float* __restrict__ out) {
  __shared__ short  lds[TILE * LDS_ROWW];   // 128 x 136 bf16 = 34816 B
  __shared__ float  csum_lds[4][TILE];      // per-wave column-sum partials
  __shared__ double sred[256];
  __shared__ int    lastFlag;

  const int tid  = threadIdx.x;
  const int wave = tid >> 6;
  const int lane = tid & 63;
  const int lr   = lane & 15;          // A-row / B-col / C-col within tile
  const int quad = lane >> 4;          // k-group for A/B, row-group for C

  // ---- decode flat job id -> (I, J) with I <= J over NT=64 ----
  // base(I) = I*(2*NT - I + 1)/2 ; float guess + integer fixup.
  const int j = blockIdx.x;
  int I = (int)((129.0f - sqrtf(16641.0f - 8.0f * (float)j)) * 0.5f);
  I = I < 0 ? 0 : (I > NT - 1 ? NT - 1 : I);
  while (I < NT - 1 && (I + 1) * (2 * NT - I) / 2 <= j) ++I;
  while (I > 0 && I * (2 * NT - I + 1) / 2 > j) --I;
  const int J = I + (j - I * (2 * NT - I + 1) / 2);
  const bool diag = (I == J);
  const int R0 = I * TILE;
  const int C0 = J * TILE;

  const ushort* zp = (const ushort*)z;

  // ---- A fragments pinned in VGPRs: rows R0 + wave*32 + rt*16 + lr ----
  short8 afrag[2][4];
  #pragma unroll
  for (int rt = 0; rt < 2; rt++) {
    const int arow = R0 + wave * 32 + rt * 16 + lr;
    const short8* ap = (const short8*)(zp + (size_t)arow * DIMS + quad * 8);
    afrag[rt][0] = ap[0];
    afrag[rt][1] = ap[4];   // +32 shorts
    afrag[rt][2] = ap[8];
    afrag[rt][3] = ap[12];
  }

  // ---- stage B tile: 128 cols x 128 dims (2048 short8, 8 per thread) ----
  {
    const short8* src = (const short8*)(zp + (size_t)C0 * DIMS);
    #pragma unroll
    for (int i = 0; i < 8; i++) {
      int idx  = tid + 256 * i;
      int row  = idx >> 4;             // 16 short8 per logical row
      int col8 = idx & 15;
      *(short8*)&lds[row * LDS_ROWW + col8 * 8] = src[idx];
    }
  }
  __syncthreads();

  float rowsum[2][4];
  #pragma unroll
  for (int rt = 0; rt < 2; rt++)
    #pragma unroll
    for (int r = 0; r < 4; r++) rowsum[rt][r] = 0.0f;

  #pragma unroll 2
  for (int t = 0; t < 8; t++) {        // 8 column tiles of 16
    const short8* bp = (const short8*)&lds[(t * 16 + lr) * LDS_ROWW + quad * 8];
    short8 b0 = bp[0];
    short8 b1 = bp[4];
    short8 b2 = bp[8];
    short8 b3 = bp[12];
    float ctile = 0.0f;
    #pragma unroll
    for (int rt = 0; rt < 2; rt++) {
      float4v acc = {0.0f, 0.0f, 0.0f, 0.0f};
      acc = __builtin_amdgcn_mfma_f32_16x16x32_bf16(afrag[rt][0], b0, acc, 0, 0, 0);
      acc = __builtin_amdgcn_mfma_f32_16x16x32_bf16(afrag[rt][1], b1, acc, 0, 0, 0);
      acc = __builtin_amdgcn_mfma_f32_16x16x32_bf16(afrag[rt][2], b2, acc, 0, 0, 0);
      acc = __builtin_amdgcn_mfma_f32_16x16x32_bf16(afrag[rt][3], b3, acc, 0, 0, 0);
      // exp(sim/T) = exp2(acc) thanks to ZSCALE pre-scaling.
      #pragma unroll
      for (int r = 0; r < 4; r++) {
        float e = __builtin_amdgcn_exp2f(acc[r]);
        rowsum[rt][r] += e;
        ctile += e;
      }
    }
    if (!diag) {  // block-uniform branch
      // column sums: reduce over the wave's 32 rows (4 regs done above, now quads)
      ctile += __shfl_xor(ctile, 16, 64);
      ctile += __shfl_xor(ctile, 32, 64);
      if (quad == 0) csum_lds[wave][t * 16 + lr] = ctile;
    }
  }

  // ---- row sums: reduce across the 16 lanes of each quad ----
  #pragma unroll
  for (int m = 1; m < 16; m <<= 1)
    #pragma unroll
    for (int rt = 0; rt < 2; rt++)
      #pragma unroll
      for (int r = 0; r < 4; r++)
        rowsum[rt][r] += __shfl_xor(rowsum[rt][r], m, 64);
  if (lr == 0) {
    #pragma unroll
    for (int rt = 0; rt < 2; rt++)
      #pragma unroll
      for (int r = 0; r < 4; r++)
        atomicAdd(&denom[R0 + wave * 32 + rt * 16 + quad * 4 + r], rowsum[rt][r]);
  }

  // ---- column sums: combine 4 wave partials, one atomic per column ----
  if (!diag) {
    __syncthreads();
    if (tid < TILE) {
      float s = csum_lds[0][tid] + csum_lds[1][tid] +
                csum_lds[2][tid] + csum_lds[3][tid];
      atomicAdd(&denom[C0 + tid], s);
    }
  }

  // ---- completion protocol: last block runs finalize ----
  __threadfence();          // make this thread's atomics device-visible
  __syncthreads();          // all threads of block have fenced
  if (tid == 0) {
    unsigned int old = atomicAdd(cnt, 1u);
    lastFlag = (old == (unsigned int)(gridDim.x - 1));
  }
  __syncthreads();
  if (!lastFlag) return;

  // loss = (1/2B) * sum_r [ log(denom[r] - e^2) - 2*pos[r mod B] ]
  // denom reads via atomic RMW to stay on the device-coherent path.
  double acc = 0.0;
  for (int r = tid; r < N2; r += 256) {
    float d = atomicAdd(&denom[r], 0.0f);
    acc += (double)(logf(d - DIAG_E2) - 2.0f * pos[r & (BB - 1)]);
  }
  sred[tid] = acc;
  __syncthreads();
  for (int s = 128; s; s >>= 1) {
    if (tid < s) sred[tid] += sred[tid + s];
    __syncthreads();
  }
  if (tid == 0) out[0] = (float)(sred[0] / (double)N2);
}

// ---------------------------------------------------------------------------
extern "C" void kernel_launch(void* const* d_in, const int* in_sizes, int n_in,
                              void* d_out, int out_size, void* d_ws, size_t ws_size,
                              hipStream_t stream) {
  const float* emb_i = (const float*)d_in[0];
  const float* emb_j = (const float*)d_in[1];

  // workspace layout
  __hip_bfloat16* z = (__hip_bfloat16*)d_ws;                         // 8192*128*2 = 2 MiB
  float* pos   = (float*)((char*)d_ws + (size_t)N2 * DIMS * 2);      // 4096 f32
  float* denom = pos + BB;                                           // 8192 f32
  unsigned int* cnt = (unsigned int*)(denom + N2);                   // 1 u32

  norm_kernel<<<BB / 4, 256, 0, stream>>>(emb_i, emb_j, z, pos, denom, cnt);
  simloss_sym<<<NJOBS, 256, 0, stream>>>(z, denom, pos, cnt, (float*)d_out);
}

// Round 3
// 92.309 us; speedup vs baseline: 2.2402x; 2.2402x over previous
//
#include <hip/hip_runtime.h>
#include <hip/hip_bf16.h>
#include <math.h>

// Problem constants (B=4096, D=128, T=0.5 -> 1/T = 2)
#define BB       4096
#define N2       8192          // 2B rows of z
#define DIMS     128
#define NT       64            // number of 128-row tiles per matrix side
#define NJOBS    (NT * (NT + 1) / 2)   // 2080 upper-triangle tile jobs
#define TILE     128
#define LDS_PAD  8             // bf16 pad per row: breaks 256B-stride 16B-group conflicts
#define LDS_ROWW (DIMS + LDS_PAD)  // 136 shorts = 272 B

// z rows are pre-scaled by ZSCALE so the MFMA dot directly yields
// sim * 2*log2(e), i.e. exp(sim/T) = exp2(acc). ZSCALE^2 = 2.8853900818.
#define ZSCALE   1.6986436f
// diagonal term exp(2 * |z_r|^2) ~= exp(2) — subtracted in finalize.
#define DIAG_E2  7.38905609893065f

typedef __attribute__((ext_vector_type(8))) short short8;   // 8 x bf16 (4 VGPRs)
typedef __attribute__((ext_vector_type(4))) float float4v;  // MFMA C/D

// ---------------------------------------------------------------------------
// Kernel 1: normalize rows (fp32), compute positives (fp32), write z as
// bf16 scaled by ZSCALE. Also zeroes the denom accumulators.
// One wave per row-pair r: emb_i[r] -> z[r], emb_j[r] -> z[r+B].
// ---------------------------------------------------------------------------
__global__ __launch_bounds__(256) void norm_kernel(
    const float* __restrict__ emb_i, const float* __restrict__ emb_j,
    __hip_bfloat16* __restrict__ z, float* __restrict__ pos,
    float* __restrict__ denom) {
  if (blockIdx.x < N2 / 256) denom[blockIdx.x * 256 + threadIdx.x] = 0.0f;

  int gw   = (blockIdx.x * blockDim.x + threadIdx.x) >> 6;  // row pair
  int lane = threadIdx.x & 63;
  if (gw >= BB) return;

  const float2* ei = (const float2*)(emb_i + (size_t)gw * DIMS);
  const float2* ej = (const float2*)(emb_j + (size_t)gw * DIMS);
  float2 a = ei[lane];
  float2 b = ej[lane];

  float sa = a.x * a.x + a.y * a.y;
  float sb = b.x * b.x + b.y * b.y;
  #pragma unroll
  for (int m = 32; m; m >>= 1) {
    sa += __shfl_xor(sa, m, 64);
    sb += __shfl_xor(sb, m, 64);
  }
  float inva = 1.0f / fmaxf(sqrtf(sa), 1e-12f);
  float invb = 1.0f / fmaxf(sqrtf(sb), 1e-12f);

  float zi0 = a.x * inva, zi1 = a.y * inva;
  float zj0 = b.x * invb, zj1 = b.y * invb;

  // positive pair dot in unscaled fp32 (matches reference's fp32 einsum)
  float p = zi0 * zj0 + zi1 * zj1;
  #pragma unroll
  for (int m = 32; m; m >>= 1) p += __shfl_xor(p, m, 64);
  if (lane == 0) pos[gw] = p;

  __hip_bfloat162* zr_i = (__hip_bfloat162*)(z + (size_t)gw * DIMS);
  __hip_bfloat162* zr_j = (__hip_bfloat162*)(z + (size_t)(gw + BB) * DIMS);
  __hip_bfloat162 vi, vj;
  vi.x = __float2bfloat16(zi0 * ZSCALE); vi.y = __float2bfloat16(zi1 * ZSCALE);
  vj.x = __float2bfloat16(zj0 * ZSCALE); vj.y = __float2bfloat16(zj1 * ZSCALE);
  zr_i[lane] = vi;
  zr_j[lane] = vj;
}

// ---------------------------------------------------------------------------
// Kernel 2: symmetric fused sim-GEMM + exp2 + row/col sums.
// sim = z z^T is symmetric; job j covers the 128x128 tile (I,J), I<=J, over
// the 64x64 tile grid (2080 jobs). Off-diagonal tiles feed BOTH row sums
// (reduce over lanes, C-layout col=lane&15) and column sums (reduce over the
// 4 C-regs + shfl_xor over quads, C-layout row=quad*4+reg). Diagonal tiles
// are computed fully and feed row sums only. MFMA dot is bit-identical under
// operand transpose, so each pair contributes the same value either way.
// Block = 256 threads (4 waves); wave owns 32 rows (2 rowtiles of A pinned in
// VGPRs), B tile (128 cols x 128 dims) staged once in LDS.
// NOTE (round-1 post-mortem): NO __threadfence / completion-counter here —
// the device-scope release fence per block (cross-XCD L2 writeback) was the
// 153 µs serialization. Cross-XCD visibility for the finalize kernel comes
// from the kernel boundary instead (stream-ordered dispatch, as in round 0).
// ---------------------------------------------------------------------------
__global__ __launch_bounds__(256, 4) void simloss_sym(
    const __hip_bfloat16* __restrict__ z, float* __restrict__ denom) {
  __shared__ short lds[TILE * LDS_ROWW];   // 128 x 136 bf16 = 34816 B
  __shared__ float csum_lds[4][TILE];      // per-wave column-sum partials

  const int tid  = threadIdx.x;
  const int wave = tid >> 6;
  const int lane = tid & 63;
  const int lr   = lane & 15;          // A-row / B-col / C-col within tile
  const int quad = lane >> 4;          // k-group for A/B, row-group for C

  // ---- decode flat job id -> (I, J) with I <= J over NT=64 ----
  // base(I) = I*(2*NT - I + 1)/2 ; float guess + integer fixup.
  const int j = blockIdx.x;
  int I = (int)((129.0f - sqrtf(16641.0f - 8.0f * (float)j)) * 0.5f);
  I = I < 0 ? 0 : (I > NT - 1 ? NT - 1 : I);
  while (I < NT - 1 && (I + 1) * (2 * NT - I) / 2 <= j) ++I;
  while (I > 0 && I * (2 * NT - I + 1) / 2 > j) --I;
  const int J = I + (j - I * (2 * NT - I + 1) / 2);
  const bool diag = (I == J);
  const int R0 = I * TILE;
  const int C0 = J * TILE;

  const ushort* zp = (const ushort*)z;

  // ---- A fragments pinned in VGPRs: rows R0 + wave*32 + rt*16 + lr ----
  short8 afrag[2][4];
  #pragma unroll
  for (int rt = 0; rt < 2; rt++) {
    const int arow = R0 + wave * 32 + rt * 16 + lr;
    const short8* ap = (const short8*)(zp + (size_t)arow * DIMS + quad * 8);
    afrag[rt][0] = ap[0];
    afrag[rt][1] = ap[4];   // +32 shorts
    afrag[rt][2] = ap[8];
    afrag[rt][3] = ap[12];
  }

  // ---- stage B tile: 128 cols x 128 dims (2048 short8, 8 per thread) ----
  {
    const short8* src = (const short8*)(zp + (size_t)C0 * DIMS);
    #pragma unroll
    for (int i = 0; i < 8; i++) {
      int idx  = tid + 256 * i;
      int row  = idx >> 4;             // 16 short8 per logical row
      int col8 = idx & 15;
      *(short8*)&lds[row * LDS_ROWW + col8 * 8] = src[idx];
    }
  }
  __syncthreads();

  float rowsum[2][4];
  #pragma unroll
  for (int rt = 0; rt < 2; rt++)
    #pragma unroll
    for (int r = 0; r < 4; r++) rowsum[rt][r] = 0.0f;

  #pragma unroll 2
  for (int t = 0; t < 8; t++) {        // 8 column tiles of 16
    const short8* bp = (const short8*)&lds[(t * 16 + lr) * LDS_ROWW + quad * 8];
    short8 b0 = bp[0];
    short8 b1 = bp[4];
    short8 b2 = bp[8];
    short8 b3 = bp[12];
    float ctile = 0.0f;
    #pragma unroll
    for (int rt = 0; rt < 2; rt++) {
      float4v acc = {0.0f, 0.0f, 0.0f, 0.0f};
      acc = __builtin_amdgcn_mfma_f32_16x16x32_bf16(afrag[rt][0], b0, acc, 0, 0, 0);
      acc = __builtin_amdgcn_mfma_f32_16x16x32_bf16(afrag[rt][1], b1, acc, 0, 0, 0);
      acc = __builtin_amdgcn_mfma_f32_16x16x32_bf16(afrag[rt][2], b2, acc, 0, 0, 0);
      acc = __builtin_amdgcn_mfma_f32_16x16x32_bf16(afrag[rt][3], b3, acc, 0, 0, 0);
      // exp(sim/T) = exp2(acc) thanks to ZSCALE pre-scaling.
      #pragma unroll
      for (int r = 0; r < 4; r++) {
        float e = __builtin_amdgcn_exp2f(acc[r]);
        rowsum[rt][r] += e;
        ctile += e;
      }
    }
    if (!diag) {  // block-uniform branch
      // column sums: reduce over the wave's 32 rows (4 regs done above, now quads)
      ctile += __shfl_xor(ctile, 16, 64);
      ctile += __shfl_xor(ctile, 32, 64);
      if (quad == 0) csum_lds[wave][t * 16 + lr] = ctile;
    }
  }

  // ---- row sums: reduce across the 16 lanes of each quad ----
  #pragma unroll
  for (int m = 1; m < 16; m <<= 1)
    #pragma unroll
    for (int rt = 0; rt < 2; rt++)
      #pragma unroll
      for (int r = 0; r < 4; r++)
        rowsum[rt][r] += __shfl_xor(rowsum[rt][r], m, 64);
  if (lr == 0) {
    #pragma unroll
    for (int rt = 0; rt < 2; rt++)
      #pragma unroll
      for (int r = 0; r < 4; r++)
        atomicAdd(&denom[R0 + wave * 32 + rt * 16 + quad * 4 + r], rowsum[rt][r]);
  }

  // ---- column sums: combine 4 wave partials, one atomic per column ----
  if (!diag) {
    __syncthreads();
    if (tid < TILE) {
      float s = csum_lds[0][tid] + csum_lds[1][tid] +
                csum_lds[2][tid] + csum_lds[3][tid];
      atomicAdd(&denom[C0 + tid], s);
    }
  }
}

// ---------------------------------------------------------------------------
// Kernel 3: loss = (1/2B) * sum_r [ log(denom[r] - e^2) - 2*pos[r mod B] ]
// Single block; double accumulation. Kernel boundary gives cross-XCD
// visibility of the atomics (same mechanism as the round-0 baseline).
// ---------------------------------------------------------------------------
__global__ __launch_bounds__(256) void finalize(
    const float* __restrict__ denom, const float* __restrict__ pos,
    float* __restrict__ out) {
  __shared__ double sred[256];
  int tid = threadIdx.x;
  double acc = 0.0;
  for (int r = tid; r < N2; r += 256) {
    acc += (double)(logf(denom[r] - DIAG_E2) - 2.0f * pos[r & (BB - 1)]);
  }
  sred[tid] = acc;
  __syncthreads();
  for (int s = 128; s; s >>= 1) {
    if (tid < s) sred[tid] += sred[tid + s];
    __syncthreads();
  }
  if (tid == 0) out[0] = (float)(sred[0] / (double)N2);
}

// ---------------------------------------------------------------------------
extern "C" void kernel_launch(void* const* d_in, const int* in_sizes, int n_in,
                              void* d_out, int out_size, void* d_ws, size_t ws_size,
                              hipStream_t stream) {
  const float* emb_i = (const float*)d_in[0];
  const float* emb_j = (const float*)d_in[1];

  // workspace layout
  __hip_bfloat16* z = (__hip_bfloat16*)d_ws;                         // 8192*128*2 = 2 MiB
  float* pos   = (float*)((char*)d_ws + (size_t)N2 * DIMS * 2);      // 4096 f32
  float* denom = pos + BB;                                           // 8192 f32

  norm_kernel<<<BB / 4, 256, 0, stream>>>(emb_i, emb_j, z, pos, denom);
  simloss_sym<<<NJOBS, 256, 0, stream>>>(z, denom);
  finalize<<<1, 256, 0, stream>>>(denom, pos, (float*)d_out);
}

// Round 4
// 83.814 us; speedup vs baseline: 2.4673x; 1.1014x over previous
//
#include <hip/hip_runtime.h>
#include <hip/hip_bf16.h>
#include <math.h>

// Problem constants (B=4096, D=128, T=0.5 -> 1/T = 2)
#define BB       4096
#define N2       8192          // 2B rows of z
#define DIMS     128
#define NT       64            // number of 128-row tiles per matrix side
#define NJOBS    (NT * (NT + 1) / 2)   // 2080 upper-triangle tile jobs
#define TILE     128
#define LDS_PAD  8             // bf16 pad per row: breaks 256B-stride 16B-group conflicts
#define LDS_ROWW (DIMS + LDS_PAD)  // 136 shorts = 272 B

// z rows are pre-scaled by ZSCALE so the MFMA dot directly yields
// sim * 2*log2(e), i.e. exp(sim/T) = exp2(acc). ZSCALE^2 = 2.8853900818.
#define ZSCALE   1.6986436f
// diagonal term exp(2 * |z_r|^2) ~= exp(2) — subtracted in reduce.
#define DIAG_E2  7.38905609893065f

typedef __attribute__((ext_vector_type(8))) short short8;   // 8 x bf16 (4 VGPRs)
typedef __attribute__((ext_vector_type(4))) float float4v;  // MFMA C/D

// ---------------------------------------------------------------------------
// Kernel 1: normalize rows (fp32), compute positives (fp32), write z as
// bf16 scaled by ZSCALE. One wave per row-pair r: emb_i[r] -> z[r],
// emb_j[r] -> z[r+B]. (No denom buffer anymore — partials P is written
// fully by kernel 2, so nothing needs zero-init.)
// ---------------------------------------------------------------------------
__global__ __launch_bounds__(256) void norm_kernel(
    const float* __restrict__ emb_i, const float* __restrict__ emb_j,
    __hip_bfloat16* __restrict__ z, float* __restrict__ pos) {
  int gw   = (blockIdx.x * blockDim.x + threadIdx.x) >> 6;  // row pair
  int lane = threadIdx.x & 63;
  if (gw >= BB) return;

  const float2* ei = (const float2*)(emb_i + (size_t)gw * DIMS);
  const float2* ej = (const float2*)(emb_j + (size_t)gw * DIMS);
  float2 a = ei[lane];
  float2 b = ej[lane];

  float sa = a.x * a.x + a.y * a.y;
  float sb = b.x * b.x + b.y * b.y;
  #pragma unroll
  for (int m = 32; m; m >>= 1) {
    sa += __shfl_xor(sa, m, 64);
    sb += __shfl_xor(sb, m, 64);
  }
  float inva = 1.0f / fmaxf(sqrtf(sa), 1e-12f);
  float invb = 1.0f / fmaxf(sqrtf(sb), 1e-12f);

  float zi0 = a.x * inva, zi1 = a.y * inva;
  float zj0 = b.x * invb, zj1 = b.y * invb;

  // positive pair dot in unscaled fp32 (matches reference's fp32 einsum)
  float p = zi0 * zj0 + zi1 * zj1;
  #pragma unroll
  for (int m = 32; m; m >>= 1) p += __shfl_xor(p, m, 64);
  if (lane == 0) pos[gw] = p;

  __hip_bfloat162* zr_i = (__hip_bfloat162*)(z + (size_t)gw * DIMS);
  __hip_bfloat162* zr_j = (__hip_bfloat162*)(z + (size_t)(gw + BB) * DIMS);
  __hip_bfloat162 vi, vj;
  vi.x = __float2bfloat16(zi0 * ZSCALE); vi.y = __float2bfloat16(zi1 * ZSCALE);
  vj.x = __float2bfloat16(zj0 * ZSCALE); vj.y = __float2bfloat16(zj1 * ZSCALE);
  zr_i[lane] = vi;
  zr_j[lane] = vj;
}

// ---------------------------------------------------------------------------
// Kernel 2: symmetric fused sim-GEMM + exp2 -> PRIVATE partials (no atomics).
// Round-3 post-mortem: FLOPs halved vs round 0 but time unchanged (~38 µs)
// => overhead-bound; two-point model attributes ~24 µs to the 325 K
// device-scope atomicAdds into the 32 KB denom array (contended cross-XCD
// RMWs; r1 WRITE_SIZE 5.2 MB = atomic write-through). Replaced by plain
// coalesced stores into P[64][64][128]: block (I,J), I<J writes row-partials
// to P[I][J][:] and col-partials to P[J][I][:]; diag block writes P[I][I][:].
// Every cell written exactly once; reduction deferred to kernel 3.
// MFMA dot is bit-identical under operand transpose (same products, same
// reduction tree), so symmetry reuse is exact.
// ---------------------------------------------------------------------------
__global__ __launch_bounds__(256, 4) void simloss_sym(
    const __hip_bfloat16* __restrict__ z, float* __restrict__ P) {
  __shared__ short lds[TILE * LDS_ROWW];   // 128 x 136 bf16 = 34816 B
  __shared__ float csum_lds[4][TILE];      // per-wave column-sum partials

  const int tid  = threadIdx.x;
  const int wave = tid >> 6;
  const int lane = tid & 63;
  const int lr   = lane & 15;          // A-row / B-col / C-col within tile
  const int quad = lane >> 4;          // k-group for A/B, row-group for C

  // ---- decode flat job id -> (I, J) with I <= J over NT=64 ----
  // base(I) = I*(2*NT - I + 1)/2 ; float guess + integer fixup.
  const int j = blockIdx.x;
  int I = (int)((129.0f - sqrtf(16641.0f - 8.0f * (float)j)) * 0.5f);
  I = I < 0 ? 0 : (I > NT - 1 ? NT - 1 : I);
  while (I < NT - 1 && (I + 1) * (2 * NT - I) / 2 <= j) ++I;
  while (I > 0 && I * (2 * NT - I + 1) / 2 > j) --I;
  const int J = I + (j - I * (2 * NT - I + 1) / 2);
  const bool diag = (I == J);
  const int R0 = I * TILE;
  const int C0 = J * TILE;

  const ushort* zp = (const ushort*)z;

  // ---- A fragments pinned in VGPRs: rows R0 + wave*32 + rt*16 + lr ----
  short8 afrag[2][4];
  #pragma unroll
  for (int rt = 0; rt < 2; rt++) {
    const int arow = R0 + wave * 32 + rt * 16 + lr;
    const short8* ap = (const short8*)(zp + (size_t)arow * DIMS + quad * 8);
    afrag[rt][0] = ap[0];
    afrag[rt][1] = ap[4];   // +32 shorts
    afrag[rt][2] = ap[8];
    afrag[rt][3] = ap[12];
  }

  // ---- stage B tile: 128 cols x 128 dims (2048 short8, 8 per thread) ----
  {
    const short8* src = (const short8*)(zp + (size_t)C0 * DIMS);
    #pragma unroll
    for (int i = 0; i < 8; i++) {
      int idx  = tid + 256 * i;
      int row  = idx >> 4;             // 16 short8 per logical row
      int col8 = idx & 15;
      *(short8*)&lds[row * LDS_ROWW + col8 * 8] = src[idx];
    }
  }
  __syncthreads();

  float rowsum[2][4];
  #pragma unroll
  for (int rt = 0; rt < 2; rt++)
    #pragma unroll
    for (int r = 0; r < 4; r++) rowsum[rt][r] = 0.0f;

  #pragma unroll 2
  for (int t = 0; t < 8; t++) {        // 8 column tiles of 16
    const short8* bp = (const short8*)&lds[(t * 16 + lr) * LDS_ROWW + quad * 8];
    short8 b0 = bp[0];
    short8 b1 = bp[4];
    short8 b2 = bp[8];
    short8 b3 = bp[12];
    float ctile = 0.0f;
    #pragma unroll
    for (int rt = 0; rt < 2; rt++) {
      float4v acc = {0.0f, 0.0f, 0.0f, 0.0f};
      acc = __builtin_amdgcn_mfma_f32_16x16x32_bf16(afrag[rt][0], b0, acc, 0, 0, 0);
      acc = __builtin_amdgcn_mfma_f32_16x16x32_bf16(afrag[rt][1], b1, acc, 0, 0, 0);
      acc = __builtin_amdgcn_mfma_f32_16x16x32_bf16(afrag[rt][2], b2, acc, 0, 0, 0);
      acc = __builtin_amdgcn_mfma_f32_16x16x32_bf16(afrag[rt][3], b3, acc, 0, 0, 0);
      // exp(sim/T) = exp2(acc) thanks to ZSCALE pre-scaling.
      #pragma unroll
      for (int r = 0; r < 4; r++) {
        float e = __builtin_amdgcn_exp2f(acc[r]);
        rowsum[rt][r] += e;
        ctile += e;
      }
    }
    if (!diag) {  // block-uniform branch
      // column sums: reduce over the wave's 32 rows (4 regs done above, now quads)
      ctile += __shfl_xor(ctile, 16, 64);
      ctile += __shfl_xor(ctile, 32, 64);
      if (quad == 0) csum_lds[wave][t * 16 + lr] = ctile;
    }
  }

  // ---- row sums: reduce across the 16 lanes of each quad, store float4 ----
  #pragma unroll
  for (int m = 1; m < 16; m <<= 1)
    #pragma unroll
    for (int rt = 0; rt < 2; rt++)
      #pragma unroll
      for (int r = 0; r < 4; r++)
        rowsum[rt][r] += __shfl_xor(rowsum[rt][r], m, 64);
  if (lr == 0) {
    // lane (quad q) holds rows quad*4 + 0..3 of its rowtile: one float4 store
    float* Prow = P + ((size_t)I * NT + J) * TILE + wave * 32;
    #pragma unroll
    for (int rt = 0; rt < 2; rt++) {
      float4v v = {rowsum[rt][0], rowsum[rt][1], rowsum[rt][2], rowsum[rt][3]};
      *(float4v*)&Prow[rt * 16 + quad * 4] = v;
    }
  }

  // ---- column sums: combine 4 wave partials, coalesced store ----
  if (!diag) {
    __syncthreads();
    if (tid < TILE) {
      float s = csum_lds[0][tid] + csum_lds[1][tid] +
                csum_lds[2][tid] + csum_lds[3][tid];
      P[((size_t)J * NT + I) * TILE + tid] = s;
    }
  }
}

// ---------------------------------------------------------------------------
// Kernel 3: per-row reduction of P + log term. 32 blocks x 256 threads,
// one thread per row r: denom[r] = sum_J P[r>>7][J][r&127] (fp32, fixed
// order), term = log(denom - e^2) - 2*pos[r mod B]; block double-reduce.
// ---------------------------------------------------------------------------
__global__ __launch_bounds__(256) void reduce_rows(
    const float* __restrict__ P, const float* __restrict__ pos,
    double* __restrict__ bpart) {
  __shared__ double sred[256];
  const int tid = threadIdx.x;
  const int r   = blockIdx.x * 256 + tid;       // 32*256 = 8192 rows
  const int I   = r >> 7;
  const int rr  = r & (TILE - 1);

  const float* p = P + (size_t)I * NT * TILE + rr;
  float acc = 0.0f;
  #pragma unroll 8
  for (int J = 0; J < NT; J++) acc += p[(size_t)J * TILE];

  double term = (double)(logf(acc - DIAG_E2) - 2.0f * pos[r & (BB - 1)]);
  sred[tid] = term;
  __syncthreads();
  for (int s = 128; s; s >>= 1) {
    if (tid < s) sred[tid] += sred[tid + s];
    __syncthreads();
  }
  if (tid == 0) bpart[blockIdx.x] = sred[0];
}

// ---------------------------------------------------------------------------
// Kernel 4: fold 32 block partials into the scalar loss. One wave.
// ---------------------------------------------------------------------------
__global__ __launch_bounds__(64) void final_sum(
    const double* __restrict__ bpart, float* __restrict__ out) {
  int tid = threadIdx.x;
  double v = (tid < 32) ? bpart[tid] : 0.0;
  #pragma unroll
  for (int m = 32; m; m >>= 1) v += __shfl_xor(v, m, 64);
  if (tid == 0) out[0] = (float)(v / (double)N2);
}

// ---------------------------------------------------------------------------
extern "C" void kernel_launch(void* const* d_in, const int* in_sizes, int n_in,
                              void* d_out, int out_size, void* d_ws, size_t ws_size,
                              hipStream_t stream) {
  const float* emb_i = (const float*)d_in[0];
  const float* emb_j = (const float*)d_in[1];

  // workspace layout
  __hip_bfloat16* z = (__hip_bfloat16*)d_ws;                       // 2 MiB
  float* pos   = (float*)((char*)d_ws + (size_t)N2 * DIMS * 2);    // 4096 f32
  float* P     = pos + BB;                                         // 64*64*128 f32 = 2 MiB
  double* bpart = (double*)(P + (size_t)NT * NT * TILE);           // 32 f64

  norm_kernel<<<BB / 4, 256, 0, stream>>>(emb_i, emb_j, z, pos);
  simloss_sym<<<NJOBS, 256, 0, stream>>>(z, P);
  reduce_rows<<<N2 / 256, 256, 0, stream>>>(P, pos, bpart);
  final_sum<<<1, 64, 0, stream>>>(bpart, (float*)d_out);
}